// Round 7
// baseline (397.693 us; speedup 1.0000x reference)
//
#include <hip/hip_runtime.h>

// GlobalMaxAvgPool: segment max + segment mean, N=2e6, C=128, B=32, ids sorted.
// Memory-bound: 1.03 GB read -> floor ~167 us @ 6.3 TB/s.
// R7: single-variable test vs R6 -- WAVE-CONTIGUOUS sequential streams.
// Each wave owns 256 contiguous rows (128 KB) and walks them linearly
// (1 KB/step, unroll 4 -> 4 KB in flight, imm-offset friendly). Cached loads
// (NOT nontemporal -- that was R2/R5's confound), full occupancy (256,8),
// per-wave shfl_xor reduce, plain stores, zero global atomics.

using f32x4 = __attribute__((ext_vector_type(4))) float;
#define INFF __builtin_huge_valf()

#define CHUNK  1024               // rows per block
#define WPB    4                  // waves per block
#define WCHUNK (CHUNK / WPB)      // 256 rows per wave (128 KB)
#define MAXR   8                  // max runs per wave (data: <=2; 62K-row segs)
#define SENT   0x7fffffff

// ws layout: hdr int2[nw*MAXR] at 0 (<=512 KB); partials at 1 MB (64 MB)
#define OFF_PART (1u << 20)

// C==128: 32 lanes x float4 = one row; wave reads rows (r, r+1) per step.
__global__ __launch_bounds__(256, 8)
void gp_main(const float* __restrict__ feat, const int* __restrict__ ids,
             int2* __restrict__ hdr, float* __restrict__ part, int N) {
    const int t     = threadIdx.x;
    const int wv    = t >> 6;        // wave in block 0..3
    const int lane  = t & 63;
    const int slot2 = (t >> 5) & 1;  // row parity within wave
    const int lane5 = t & 31;

    __shared__ int sids[CHUNK];
    __shared__ int srb[34];          // block run boundaries (local row idx)
    __shared__ int sbuf[32];
    __shared__ int snb;

    int bstart = blockIdx.x * CHUNK;
    int bend   = bstart + CHUNK; if (bend > N) bend = N;
    int blen   = bend - bstart;      // may be <= 0 only if overlaunched (not here)

    // block id slice -> LDS (coalesced 4 KB)
    for (int i = t; i < blen; i += 256) sids[i] = ids[bstart + i];
    if (t == 0) snb = 0;
    __syncthreads();
    for (int i = t; i < blen; i += 256)
        if (i > 0 && sids[i] != sids[i - 1]) {
            int p = atomicAdd(&snb, 1);          // <=31 entries; order fixed by sort
            sbuf[p] = i;
        }
    __syncthreads();
    int nb = snb;                                // uniform
    if (t == 0) {
        for (int a = 1; a < nb; ++a) {           // insertion sort (tiny)
            int v = sbuf[a]; int j = a - 1;
            while (j >= 0 && sbuf[j] > v) { sbuf[j + 1] = sbuf[j]; --j; }
            sbuf[j + 1] = v;
        }
        srb[0] = 0;
        for (int a = 0; a < nb; ++a) srb[a + 1] = sbuf[a];
        srb[nb + 1] = blen > 0 ? blen : 0;
    }
    __syncthreads();

    const int gw  = blockIdx.x * WPB + wv;       // global wave id
    const int wsl = wv * WCHUNK;                 // local wave start row
    int wel = wsl + WCHUNK; if (wel > blen) wel = blen;

    const f32x4* __restrict__ frow = reinterpret_cast<const f32x4*>(feat);

    int lr = 0;                                  // runs emitted by this wave
    for (int j = 0; j <= nb; ++j) {              // clip block runs to wave range
        int lrs = srb[j]     > wsl ? srb[j]     : wsl;
        int lre = srb[j + 1] < wel ? srb[j + 1] : wel;
        if (lre <= lrs || lr >= MAXR) continue;  // wave-uniform condition
        int seg = sids[lrs];
        int rs = bstart + lrs, re = bstart + lre;

        f32x4 vmax = {-INFF, -INFF, -INFF, -INFF};
        f32x4 vsum = {0.f, 0.f, 0.f, 0.f};
        #pragma unroll 4
        for (int r = rs + slot2; r < re; r += 2) {       // wave: 1 KB/step, sequential
            f32x4 f = frow[(size_t)r * 32 + lane5];
            vmax[0] = fmaxf(vmax[0], f[0]);
            vmax[1] = fmaxf(vmax[1], f[1]);
            vmax[2] = fmaxf(vmax[2], f[2]);
            vmax[3] = fmaxf(vmax[3], f[3]);
            vsum += f;
        }
        // combine parity halves in-register: lane l <-> l^32
        #pragma unroll
        for (int k = 0; k < 4; ++k) {
            vmax[k] = fmaxf(vmax[k], __shfl_xor(vmax[k], 32));
            vsum[k] += __shfl_xor(vsum[k], 32);
        }
        // wave partial: 128 max | 128 sum
        float* p = &part[(size_t)(gw * MAXR + lr) * 256 + slot2 * 128 + lane5 * 4];
        if (slot2 == 0) { p[0]=vmax[0]; p[1]=vmax[1]; p[2]=vmax[2]; p[3]=vmax[3]; }
        else            { p[0]=vsum[0]; p[1]=vsum[1]; p[2]=vsum[2]; p[3]=vsum[3]; }
        if (lane == 0) hdr[gw * MAXR + lr] = make_int2(seg, lre - lrs);
        ++lr;
    }
    if (lane == 0)                                // sentinel every call (determinism)
        for (int r = lr; r < MAXR; ++r) hdr[gw * MAXR + r] = make_int2(SENT, 0);
}

// One block per segment. F[w] = hdr[w*MAXR].x is monotonic in w (waves ordered
// by row; tail empties = SENT) -> binary search wave range, scan w/ early break.
// hdr/partials L2-hot. Fixed order -> deterministic. Writes ALL of d_out.
__global__ void gp_reduce(const int2* __restrict__ hdr,
                          const float* __restrict__ part,
                          float* __restrict__ out, int nw) {
    int b = blockIdx.x;
    int t = threadIdx.x;   // t<128: max chan t ; t>=128: sum chan t-128

    int lo = 0, hi = nw;
    while (lo < hi) { int mid = (lo + hi) >> 1; if (hdr[(size_t)mid * MAXR].x < b) lo = mid + 1; else hi = mid; }
    int a = lo > 0 ? lo - 1 : 0;                 // straddling wave has F == b-1
    int lo2 = lo, hi2 = nw;
    while (lo2 < hi2) { int mid = (lo2 + hi2) >> 1; if (hdr[(size_t)mid * MAXR].x < b + 1) lo2 = mid + 1; else hi2 = mid; }
    int c = lo2 - 1;

    float m  = -INFF;
    float su = 0.f;
    int   cnt = 0;
    for (int w = a; w <= c; ++w) {
        #pragma unroll
        for (int r = 0; r < MAXR; ++r) {
            int2 h = hdr[(size_t)w * MAXR + r];  // uniform -> broadcast
            if (h.x == b) {
                float v = part[((size_t)w * MAXR + r) * 256 + t];
                m   = fmaxf(m, v);               // meaningful when t<128
                su += v;                         // meaningful when t>=128
                cnt += h.y;
            } else if (h.x > b) break;           // runs ascending + sentinel
        }
    }
    out[b * 256 + t] = (t < 128) ? m : su / fmaxf((float)cnt, 1.0f);
}

extern "C" void kernel_launch(void* const* d_in, const int* in_sizes, int n_in,
                              void* d_out, int out_size, void* d_ws, size_t ws_size,
                              hipStream_t stream) {
    const float* feat = (const float*)d_in[0];
    const int*   ids  = (const int*)d_in[1];
    int N = in_sizes[1];
    int C = (N > 0) ? (in_sizes[0] / N) : 128;   // 128
    int B = out_size / (2 * C);                  // 32
    float* out_f = (float*)d_out;

    char*  wsb  = (char*)d_ws;
    int2*  hdr  = (int2*)wsb;                    // nw*MAXR int2 (<=512 KB)
    float* part = (float*)(wsb + OFF_PART);      // nw*MAXR*256 floats (64 MB)

    int nblk = (N + CHUNK - 1) / CHUNK;          // 1954
    int nw   = nblk * WPB;                       // 7816 waves

    gp_main<<<nblk, 256, 0, stream>>>(feat, ids, hdr, part, N);
    gp_reduce<<<B, 256, 0, stream>>>(hdr, part, out_f, nw);
}

// Round 8
// 239.963 us; speedup vs baseline: 1.6573x; 1.6573x over previous
//
#include <hip/hip_runtime.h>

// GlobalMaxAvgPool: segment max + segment mean, N=2e6, C=128, B=32, ids sorted.
// Memory-bound: 1.03 GB read -> floor ~167 us @ 6.3 TB/s.
// R8 = R6 (champion: block-contiguous chunk, 8-row slot interleave, cached
// loads, LDS id-slice boundary detect, zero atomics) with ONE change:
// manual 8-deep unroll -> 8 outstanding loads per wave at 4KB stride
// (addresses span 0..28KB ~= 8 HBM channels). Theory: R7's collapse shows
// per-wave *contiguous* outstanding loads serialize on a channel; spreading
// them is what makes R6 fast; deeper spread -> better latency tolerance.

using f32x4 = __attribute__((ext_vector_type(4))) float;
#define INFF __builtin_huge_valf()

#define BLOCKS 2048
#define MAXR   32        // max runs per block == B (ids ascending, <=32 values)

// ws layout: hdr int2[BLOCKS*MAXR] at 0 (512 KB); partials at 1 MB (64 MB)
#define OFF_PART (1u << 20)

#define ACC(f) do { \
    vmax[0] = fmaxf(vmax[0], (f)[0]); \
    vmax[1] = fmaxf(vmax[1], (f)[1]); \
    vmax[2] = fmaxf(vmax[2], (f)[2]); \
    vmax[3] = fmaxf(vmax[3], (f)[3]); \
    vsum += (f); } while (0)

// C==128: 32 lanes x float4 = one row; 8 row-slots stride-8 interleave.
// chunk <= 1024 assumed (N=2M, BLOCKS=2048 -> chunk=977).
__global__ __launch_bounds__(256, 8)
void gp_main(const float* __restrict__ feat, const int* __restrict__ ids,
             int2* __restrict__ hdr, float* __restrict__ part, int N, int chunk) {
    const int t     = threadIdx.x;
    const int slot  = t >> 5;        // 0..7
    const int lane5 = t & 31;
    const int c0    = lane5 * 4;

    __shared__ int   sids[1024];
    __shared__ int   srb[MAXR + 2];  // run boundaries (local row idx)
    __shared__ int   sbuf[MAXR];
    __shared__ int   snb;
    __shared__ float lmax[8][132];   // +4 pad
    __shared__ float lsum[8][132];

    int start = blockIdx.x * chunk;
    int end   = start + chunk;
    if (end > N) end = N;
    int len = end - start;

    if (len <= 0) {
        for (int j = t; j < MAXR; j += 256)
            hdr[blockIdx.x * MAXR + j] = make_int2(0x7fffffff, 0);
        return;
    }

    // local id slice -> LDS (coalesced 4KB, overlapped across 2048 blocks)
    for (int i = t; i < len; i += 256) sids[i] = ids[start + i];
    if (t == 0) snb = 0;
    __syncthreads();

    // boundary detect (parallel; LDS-atomic order canonicalized by sort)
    for (int i = t; i < len; i += 256)
        if (i > 0 && sids[i] != sids[i - 1]) {
            int p = atomicAdd(&snb, 1);   // p <= 30 < MAXR (B=32)
            sbuf[p] = i;
        }
    __syncthreads();
    int nb = snb;                         // uniform
    if (t == 0) {
        for (int a = 1; a < nb; ++a) {    // insertion sort (tiny)
            int v = sbuf[a]; int j2 = a - 1;
            while (j2 >= 0 && sbuf[j2] > v) { sbuf[j2 + 1] = sbuf[j2]; --j2; }
            sbuf[j2 + 1] = v;
        }
        srb[0] = 0;
        for (int a = 0; a < nb; ++a) srb[a + 1] = sbuf[a];
        srb[nb + 1] = len;
    }
    __syncthreads();

    const f32x4* __restrict__ frow = reinterpret_cast<const f32x4*>(feat);

    for (int j = 0; j <= nb; ++j) {       // uniform run loop
        int lrs = srb[j], lre = srb[j + 1];
        int seg = sids[lrs];
        int rs = start + lrs, re = start + lre;

        f32x4 vmax = {-INFF, -INFF, -INFF, -INFF};
        f32x4 vsum = {0.f, 0.f, 0.f, 0.f};

        int r = rs + slot;
        // 8-deep: 8 outstanding loads at 4KB stride (rows r, r+8, .., r+56)
        for (; r + 56 < re; r += 64) {
            int b0 = r * 32 + lane5;               // fits 32-bit (N*32 = 64M)
            f32x4 f0 = frow[b0 +   0];
            f32x4 f1 = frow[b0 + 256];
            f32x4 f2 = frow[b0 + 512];
            f32x4 f3 = frow[b0 + 768];
            f32x4 f4 = frow[b0 + 1024];
            f32x4 f5 = frow[b0 + 1280];
            f32x4 f6 = frow[b0 + 1536];
            f32x4 f7 = frow[b0 + 1792];
            ACC(f0); ACC(f1); ACC(f2); ACC(f3);
            ACC(f4); ACC(f5); ACC(f6); ACC(f7);
        }
        // remainder: same shape as R6's loop
        #pragma unroll 4
        for (; r < re; r += 8) {
            f32x4 f = frow[r * 32 + lane5];
            ACC(f);
        }

        // block LDS reduce: 8 contributors per channel
        lmax[slot][c0 + 0] = vmax[0]; lmax[slot][c0 + 1] = vmax[1];
        lmax[slot][c0 + 2] = vmax[2]; lmax[slot][c0 + 3] = vmax[3];
        lsum[slot][c0 + 0] = vsum[0]; lsum[slot][c0 + 1] = vsum[1];
        lsum[slot][c0 + 2] = vsum[2]; lsum[slot][c0 + 3] = vsum[3];
        __syncthreads();

        if (t < 128) {
            float m  = lmax[0][t];
            float su = lsum[0][t];
            #pragma unroll
            for (int s = 1; s < 8; ++s) {
                m   = fmaxf(m, lmax[s][t]);
                su += lsum[s][t];
            }
            size_t base = (size_t)(blockIdx.x * MAXR + j) * 256;
            part[base + t]       = m;
            part[base + 128 + t] = su;
        }
        if (t == 0) hdr[blockIdx.x * MAXR + j] = make_int2(seg, lre - lrs);
        __syncthreads();
    }
    // sentinel unused slots every call (ws not re-poisoned; determinism)
    for (int j = nb + 1 + t; j < MAXR; j += 256)
        hdr[blockIdx.x * MAXR + j] = make_int2(0x7fffffff, 0);
}

// One block per segment. F[k] = hdr[k*MAXR].x monotonic in k -> binary search
// block range, scan with early break. hdr/partials L2-hot. Deterministic.
__global__ void gp_reduce(const int2* __restrict__ hdr,
                          const float* __restrict__ part,
                          float* __restrict__ out, int nblocks) {
    int b = blockIdx.x;
    int t = threadIdx.x;   // t<128: max chan t ; t>=128: sum chan t-128

    int lo = 0, hi = nblocks;
    while (lo < hi) { int mid = (lo + hi) >> 1; if (hdr[mid * MAXR].x < b) lo = mid + 1; else hi = mid; }
    int a = lo > 0 ? lo - 1 : 0;
    int lo2 = lo, hi2 = nblocks;
    while (lo2 < hi2) { int mid = (lo2 + hi2) >> 1; if (hdr[mid * MAXR].x < b + 1) lo2 = mid + 1; else hi2 = mid; }
    int c = lo2 - 1;

    float m  = -INFF;
    float su = 0.f;
    int   cnt = 0;
    for (int k = a; k <= c; ++k) {
        for (int r2 = 0; r2 < MAXR; ++r2) {
            int2 h = hdr[k * MAXR + r2];          // uniform -> broadcast
            if (h.x == b) {
                float v = part[(size_t)(k * MAXR + r2) * 256 + t];
                m   = fmaxf(m, v);    // meaningful when t<128
                su += v;              // meaningful when t>=128
                cnt += h.y;
            } else if (h.x > b) break;            // runs ascending + sentinel
        }
    }
    out[b * 256 + t] = (t < 128) ? m : su / fmaxf((float)cnt, 1.0f);
}

extern "C" void kernel_launch(void* const* d_in, const int* in_sizes, int n_in,
                              void* d_out, int out_size, void* d_ws, size_t ws_size,
                              hipStream_t stream) {
    const float* feat = (const float*)d_in[0];
    const int*   ids  = (const int*)d_in[1];
    int N = in_sizes[1];
    int C = (N > 0) ? (in_sizes[0] / N) : 128;   // 128
    int B = out_size / (2 * C);                  // 32
    float* out_f = (float*)d_out;

    char*  wsb  = (char*)d_ws;
    int2*  hdr  = (int2*)wsb;                    // BLOCKS*MAXR int2 (512 KB)
    float* part = (float*)(wsb + OFF_PART);      // BLOCKS*MAXR*256 floats (64 MB)

    int chunk = (N + BLOCKS - 1) / BLOCKS;       // 977

    gp_main<<<BLOCKS, 256, 0, stream>>>(feat, ids, hdr, part, N, chunk);
    gp_reduce<<<B, 256, 0, stream>>>(hdr, part, out_f, BLOCKS);
}

// Round 9
// 200.649 us; speedup vs baseline: 1.9820x; 1.1959x over previous
//
#include <hip/hip_runtime.h>

// GlobalMaxAvgPool: segment max + segment mean, N=2e6, C=128, B=32, ids sorted.
// Memory-bound: 1.03 GB read -> floor ~167 us @ 6.3 TB/s.
// R9 = R8 champion (block-contiguous chunk, 8-row slot interleave, 8-deep
// strided unroll, LDS id-slice boundary detect, zero atomics) with ONE change:
// NONTEMPORAL feature loads. NT was never isolated on the champion (R2/R5/R7
// bundled it with wave-contiguous walking, which alone costs -65%). Theory:
// zero-reuse 1GB stream pays L2/L3 allocate+evict overhead on cached reads;
// nt streams past it (fills avoid it too -- that's why they hit 6.5 TB/s).

using f32x4 = __attribute__((ext_vector_type(4))) float;
#define INFF __builtin_huge_valf()

#define BLOCKS 2048
#define MAXR   32        // max runs per block == B (ids ascending, <=32 values)

// ws layout: hdr int2[BLOCKS*MAXR] at 0 (512 KB); partials at 1 MB (64 MB)
#define OFF_PART (1u << 20)

#define ACC(f) do { \
    vmax[0] = fmaxf(vmax[0], (f)[0]); \
    vmax[1] = fmaxf(vmax[1], (f)[1]); \
    vmax[2] = fmaxf(vmax[2], (f)[2]); \
    vmax[3] = fmaxf(vmax[3], (f)[3]); \
    vsum += (f); } while (0)

// C==128: 32 lanes x float4 = one row; 8 row-slots stride-8 interleave.
// chunk <= 1024 assumed (N=2M, BLOCKS=2048 -> chunk=977).
__global__ __launch_bounds__(256, 8)
void gp_main(const float* __restrict__ feat, const int* __restrict__ ids,
             int2* __restrict__ hdr, float* __restrict__ part, int N, int chunk) {
    const int t     = threadIdx.x;
    const int slot  = t >> 5;        // 0..7
    const int lane5 = t & 31;
    const int c0    = lane5 * 4;

    __shared__ int   sids[1024];
    __shared__ int   srb[MAXR + 2];  // run boundaries (local row idx)
    __shared__ int   sbuf[MAXR];
    __shared__ int   snb;
    __shared__ float lmax[8][132];   // +4 pad
    __shared__ float lsum[8][132];

    int start = blockIdx.x * chunk;
    int end   = start + chunk;
    if (end > N) end = N;
    int len = end - start;

    if (len <= 0) {
        for (int j = t; j < MAXR; j += 256)
            hdr[blockIdx.x * MAXR + j] = make_int2(0x7fffffff, 0);
        return;
    }

    // local id slice -> LDS (coalesced 4KB, overlapped across 2048 blocks)
    for (int i = t; i < len; i += 256) sids[i] = ids[start + i];
    if (t == 0) snb = 0;
    __syncthreads();

    // boundary detect (parallel; LDS-atomic order canonicalized by sort)
    for (int i = t; i < len; i += 256)
        if (i > 0 && sids[i] != sids[i - 1]) {
            int p = atomicAdd(&snb, 1);   // p <= 30 < MAXR (B=32)
            sbuf[p] = i;
        }
    __syncthreads();
    int nb = snb;                         // uniform
    if (t == 0) {
        for (int a = 1; a < nb; ++a) {    // insertion sort (tiny)
            int v = sbuf[a]; int j2 = a - 1;
            while (j2 >= 0 && sbuf[j2] > v) { sbuf[j2 + 1] = sbuf[j2]; --j2; }
            sbuf[j2 + 1] = v;
        }
        srb[0] = 0;
        for (int a = 0; a < nb; ++a) srb[a + 1] = sbuf[a];
        srb[nb + 1] = len;
    }
    __syncthreads();

    const f32x4* __restrict__ frow = reinterpret_cast<const f32x4*>(feat);

    for (int j = 0; j <= nb; ++j) {       // uniform run loop
        int lrs = srb[j], lre = srb[j + 1];
        int seg = sids[lrs];
        int rs = start + lrs, re = start + lre;

        f32x4 vmax = {-INFF, -INFF, -INFF, -INFF};
        f32x4 vsum = {0.f, 0.f, 0.f, 0.f};

        int r = rs + slot;
        // 8-deep: 8 outstanding NT loads at 4KB stride (rows r, r+8, .., r+56)
        for (; r + 56 < re; r += 64) {
            int b0 = r * 32 + lane5;               // fits 32-bit (N*32 = 64M)
            f32x4 f0 = __builtin_nontemporal_load(&frow[b0 +    0]);
            f32x4 f1 = __builtin_nontemporal_load(&frow[b0 +  256]);
            f32x4 f2 = __builtin_nontemporal_load(&frow[b0 +  512]);
            f32x4 f3 = __builtin_nontemporal_load(&frow[b0 +  768]);
            f32x4 f4 = __builtin_nontemporal_load(&frow[b0 + 1024]);
            f32x4 f5 = __builtin_nontemporal_load(&frow[b0 + 1280]);
            f32x4 f6 = __builtin_nontemporal_load(&frow[b0 + 1536]);
            f32x4 f7 = __builtin_nontemporal_load(&frow[b0 + 1792]);
            ACC(f0); ACC(f1); ACC(f2); ACC(f3);
            ACC(f4); ACC(f5); ACC(f6); ACC(f7);
        }
        // remainder: same stride, NT as well
        #pragma unroll 4
        for (; r < re; r += 8) {
            f32x4 f = __builtin_nontemporal_load(&frow[r * 32 + lane5]);
            ACC(f);
        }

        // block LDS reduce: 8 contributors per channel
        lmax[slot][c0 + 0] = vmax[0]; lmax[slot][c0 + 1] = vmax[1];
        lmax[slot][c0 + 2] = vmax[2]; lmax[slot][c0 + 3] = vmax[3];
        lsum[slot][c0 + 0] = vsum[0]; lsum[slot][c0 + 1] = vsum[1];
        lsum[slot][c0 + 2] = vsum[2]; lsum[slot][c0 + 3] = vsum[3];
        __syncthreads();

        if (t < 128) {
            float m  = lmax[0][t];
            float su = lsum[0][t];
            #pragma unroll
            for (int s = 1; s < 8; ++s) {
                m   = fmaxf(m, lmax[s][t]);
                su += lsum[s][t];
            }
            size_t base = (size_t)(blockIdx.x * MAXR + j) * 256;
            part[base + t]       = m;
            part[base + 128 + t] = su;
        }
        if (t == 0) hdr[blockIdx.x * MAXR + j] = make_int2(seg, lre - lrs);
        __syncthreads();
    }
    // sentinel unused slots every call (ws not re-poisoned; determinism)
    for (int j = nb + 1 + t; j < MAXR; j += 256)
        hdr[blockIdx.x * MAXR + j] = make_int2(0x7fffffff, 0);
}

// One block per segment. F[k] = hdr[k*MAXR].x monotonic in k -> binary search
// block range, scan with early break. hdr/partials L2-hot. Deterministic.
__global__ void gp_reduce(const int2* __restrict__ hdr,
                          const float* __restrict__ part,
                          float* __restrict__ out, int nblocks) {
    int b = blockIdx.x;
    int t = threadIdx.x;   // t<128: max chan t ; t>=128: sum chan t-128

    int lo = 0, hi = nblocks;
    while (lo < hi) { int mid = (lo + hi) >> 1; if (hdr[mid * MAXR].x < b) lo = mid + 1; else hi = mid; }
    int a = lo > 0 ? lo - 1 : 0;
    int lo2 = lo, hi2 = nblocks;
    while (lo2 < hi2) { int mid = (lo2 + hi2) >> 1; if (hdr[mid * MAXR].x < b + 1) lo2 = mid + 1; else hi2 = mid; }
    int c = lo2 - 1;

    float m  = -INFF;
    float su = 0.f;
    int   cnt = 0;
    for (int k = a; k <= c; ++k) {
        for (int r2 = 0; r2 < MAXR; ++r2) {
            int2 h = hdr[k * MAXR + r2];          // uniform -> broadcast
            if (h.x == b) {
                float v = part[(size_t)(k * MAXR + r2) * 256 + t];
                m   = fmaxf(m, v);    // meaningful when t<128
                su += v;              // meaningful when t>=128
                cnt += h.y;
            } else if (h.x > b) break;            // runs ascending + sentinel
        }
    }
    out[b * 256 + t] = (t < 128) ? m : su / fmaxf((float)cnt, 1.0f);
}

extern "C" void kernel_launch(void* const* d_in, const int* in_sizes, int n_in,
                              void* d_out, int out_size, void* d_ws, size_t ws_size,
                              hipStream_t stream) {
    const float* feat = (const float*)d_in[0];
    const int*   ids  = (const int*)d_in[1];
    int N = in_sizes[1];
    int C = (N > 0) ? (in_sizes[0] / N) : 128;   // 128
    int B = out_size / (2 * C);                  // 32
    float* out_f = (float*)d_out;

    char*  wsb  = (char*)d_ws;
    int2*  hdr  = (int2*)wsb;                    // BLOCKS*MAXR int2 (512 KB)
    float* part = (float*)(wsb + OFF_PART);      // BLOCKS*MAXR*256 floats (64 MB)

    int chunk = (N + BLOCKS - 1) / BLOCKS;       // 977

    gp_main<<<BLOCKS, 256, 0, stream>>>(feat, ids, hdr, part, N, chunk);
    gp_reduce<<<B, 256, 0, stream>>>(hdr, part, out_f, BLOCKS);
}